// Round 1
// baseline (142.788 us; speedup 1.0000x reference)
//
#include <hip/hip_runtime.h>
#include <math.h>

namespace {

constexpr int NB = 2, NS = 128, ND = 64, NF = 256;

// workspace offsets (floats)
constexpr size_t OFF_W2   = 0;                               // [B][S(j)][F][D]
constexpr size_t SZ_W2    = (size_t)NB * NS * NF * ND;       // 4.19M
constexpr size_t OFF_P    = OFF_W2 + SZ_W2;                  // [B][S(j)][S(i)][D]
constexpr size_t SZ_P     = (size_t)NB * NS * NS * ND;       // 2.10M
constexpr size_t OFF_AT   = OFF_P + SZ_P;                    // [B][F][S(i)]  (transposed A)
constexpr size_t SZ_AT    = (size_t)NB * NF * NS;
constexpr size_t OFF_BT   = OFF_AT + SZ_AT;                  // [B][S(j)][F]  (includes gb1)
constexpr size_t SZ_BT    = (size_t)NB * NS * NF;
constexpr size_t OFF_QT   = OFF_BT + SZ_BT;                  // [B][D][S(j)]
constexpr size_t SZ_QT    = (size_t)NB * ND * NS;
constexpr size_t OFF_BIAS = OFF_QT + SZ_QT;                  // [B][D]

__device__ __forceinline__ float gelu_exact(float x) {
  return 0.5f * x * (1.0f + erff(x * 0.70710678118654752f));
}

// ---------------------------------------------------------------------------
// k0: q_t[b][d][j] = q[b][j][d];  bias_agg[b][e] = sum_d gb2[d*D+e] * sum_j q[b][j][d]
// ---------------------------------------------------------------------------
__global__ __launch_bounds__(256) void k0_qt_bias(const float* __restrict__ q,
                                                  const float* __restrict__ gb2,
                                                  float* __restrict__ q_t,
                                                  float* __restrict__ bias_agg) {
  const int b = blockIdx.x;
  const int t = threadIdx.x;
  __shared__ __align__(16) float qs[NS * ND];
  __shared__ float colsum[ND];
  const float* qb = q + (size_t)b * NS * ND;
  for (int r = 0; r < NS * ND / 256; ++r) qs[t + r * 256] = qb[t + r * 256];
  __syncthreads();
  for (int r = 0; r < NS * ND / 256; ++r) {
    const int lin = t + r * 256;
    const int j = lin >> 6, d = lin & 63;
    q_t[((size_t)b * ND + d) * NS + j] = qs[lin];
  }
  if (t < ND) {
    float s = 0.f;
    for (int j = 0; j < NS; ++j) s += qs[j * ND + t];
    colsum[t] = s;
  }
  __syncthreads();
  if (t < ND) {
    float acc = 0.f;
    for (int d = 0; d < ND; ++d) acc += gb2[d * ND + t] * colsum[d];
    bias_agg[b * ND + t] = acc;
  }
}

// ---------------------------------------------------------------------------
// k1: blocks [0, B*S)      : A_t[b][f][i], Bt[b][j][f] (+gb1)
//     blocks [B*S, B*S+B*F): W2[b][j][f][e] = sum_d q[b][j][d] * gw2[f][d*D+e]
// ---------------------------------------------------------------------------
__global__ __launch_bounds__(256) void k1_pre(const float* __restrict__ q,
                                              const float* __restrict__ gw1,
                                              const float* __restrict__ gb1,
                                              const float* __restrict__ gw2,
                                              const float* __restrict__ q_t,
                                              float* __restrict__ A_t,
                                              float* __restrict__ Bt,
                                              float* __restrict__ W2) {
  const int t = threadIdx.x;
  if (blockIdx.x < NB * NS) {
    const int b = blockIdx.x / NS, i = blockIdx.x % NS;
    __shared__ float qrow[ND];
    if (t < ND) qrow[t] = q[((size_t)b * NS + i) * ND + t];
    __syncthreads();
    const int f = t;  // 256 threads == F
    float a = 0.f, bb = gb1[f];
    #pragma unroll 8
    for (int d = 0; d < ND; ++d) {
      const float qd = qrow[d];
      a  += qd * gw1[d * NF + f];
      bb += qd * gw1[(ND + d) * NF + f];
    }
    A_t[((size_t)b * NF + f) * NS + i] = a;
    Bt[((size_t)b * NS + i) * NF + f] = bb;
  } else {
    const int idx = blockIdx.x - NB * NS;
    const int b = idx / NF, f = idx % NF;
    __shared__ __align__(16) float G[ND * ND];   // gw2 row f, [d][e]
    __shared__ __align__(16) float qt[ND * NS];  // [d][j]
    for (int r = 0; r < ND * ND / 256; ++r)
      G[t + r * 256] = gw2[(size_t)f * ND * ND + t + r * 256];
    for (int r = 0; r < ND * NS / 256; ++r)
      qt[t + r * 256] = q_t[(size_t)b * ND * NS + t + r * 256];
    __syncthreads();
    const int tj = t >> 3, te = t & 7;   // 32 x 8 thread grid
    const int j0 = tj * 4, e0 = te * 8;  // 4j x 8e register tile
    float acc[4][8];
    #pragma unroll
    for (int jj = 0; jj < 4; ++jj)
      #pragma unroll
      for (int ee = 0; ee < 8; ++ee) acc[jj][ee] = 0.f;
    #pragma unroll 4
    for (int d = 0; d < ND; ++d) {
      const float4 qv = *(const float4*)&qt[d * NS + j0];
      const float4 g0 = *(const float4*)&G[d * ND + e0];
      const float4 g1 = *(const float4*)&G[d * ND + e0 + 4];
      const float qa[4] = {qv.x, qv.y, qv.z, qv.w};
      const float ga[8] = {g0.x, g0.y, g0.z, g0.w, g1.x, g1.y, g1.z, g1.w};
      #pragma unroll
      for (int jj = 0; jj < 4; ++jj)
        #pragma unroll
        for (int ee = 0; ee < 8; ++ee) acc[jj][ee] += qa[jj] * ga[ee];
    }
    #pragma unroll
    for (int jj = 0; jj < 4; ++jj) {
      const int j = j0 + jj;
      float* dst = W2 + (((size_t)b * NS + j) * NF + f) * ND + e0;
      *(float4*)&dst[0] = make_float4(acc[jj][0], acc[jj][1], acc[jj][2], acc[jj][3]);
      *(float4*)&dst[4] = make_float4(acc[jj][4], acc[jj][5], acc[jj][6], acc[jj][7]);
    }
  }
}

// ---------------------------------------------------------------------------
// k2: one wg per (b,j): P[b][j][i][e] = sum_f gelu(A_t[b][f][i]+Bt[b][j][f]) * W2[b][j][f][e]
// ---------------------------------------------------------------------------
__global__ __launch_bounds__(256) void k2_main(const float* __restrict__ A_t,
                                               const float* __restrict__ Bt,
                                               const float* __restrict__ W2,
                                               float* __restrict__ P) {
  const int b = blockIdx.x / NS, j = blockIdx.x % NS;
  const int t = threadIdx.x;
  __shared__ float Btj[NF];
  __shared__ __align__(16) float Hc[64 * NS];  // [fc][i]
  __shared__ __align__(16) float Wc[64 * ND];  // [fc][e]
  Btj[t] = Bt[((size_t)b * NS + j) * NF + t];
  const int ty = t >> 4, tx = t & 15;  // 16 x 16
  const int i0 = ty * 8, e0 = tx * 4;  // 8i x 4e register tile
  const int ih = t & 127, fh = (t >> 7) * 32;
  float acc[8][4];
  #pragma unroll
  for (int r = 0; r < 8; ++r)
    #pragma unroll
    for (int cc = 0; cc < 4; ++cc) acc[r][cc] = 0.f;
  const float* W2bj = W2 + ((size_t)b * NS + j) * NF * ND;
  const float* Ab = A_t + (size_t)b * NF * NS;
  for (int c = 0; c < NF / 64; ++c) {
    __syncthreads();
    #pragma unroll
    for (int r = 0; r < 4; ++r) {
      *(float4*)&Wc[(t + r * 256) * 4] =
          *(const float4*)&W2bj[c * 64 * ND + (t + r * 256) * 4];
    }
    #pragma unroll 4
    for (int m = 0; m < 32; ++m) {
      const int fc = fh + m;
      const float v = Ab[(c * 64 + fc) * NS + ih] + Btj[c * 64 + fc];
      Hc[fc * NS + ih] = gelu_exact(v);
    }
    __syncthreads();
    #pragma unroll 4
    for (int fc = 0; fc < 64; ++fc) {
      const float4 h0 = *(const float4*)&Hc[fc * NS + i0];
      const float4 h1 = *(const float4*)&Hc[fc * NS + i0 + 4];
      const float4 w  = *(const float4*)&Wc[fc * ND + e0];
      const float ha[8] = {h0.x, h0.y, h0.z, h0.w, h1.x, h1.y, h1.z, h1.w};
      const float wa[4] = {w.x, w.y, w.z, w.w};
      #pragma unroll
      for (int r = 0; r < 8; ++r)
        #pragma unroll
        for (int cc = 0; cc < 4; ++cc) acc[r][cc] += ha[r] * wa[cc];
    }
  }
  float* Pbj = P + ((size_t)b * NS + j) * NS * ND;
  #pragma unroll
  for (int r = 0; r < 8; ++r) {
    *(float4*)&Pbj[(size_t)(i0 + r) * ND + e0] =
        make_float4(acc[r][0], acc[r][1], acc[r][2], acc[r][3]);
  }
}

// ---------------------------------------------------------------------------
// k3: one wg per (b,i): agg-reduce over j, LN1, MLP (gelu exact), LN2 -> out
// ---------------------------------------------------------------------------
__global__ __launch_bounds__(256) void k3_epi(const float* __restrict__ q,
                                              const float* __restrict__ P,
                                              const float* __restrict__ bias_agg,
                                              const float* __restrict__ mw1,
                                              const float* __restrict__ mb1,
                                              const float* __restrict__ mw2,
                                              const float* __restrict__ mb2,
                                              const float* __restrict__ ln1g,
                                              const float* __restrict__ ln1b,
                                              const float* __restrict__ ln2g,
                                              const float* __restrict__ ln2b,
                                              float* __restrict__ out) {
  const int b = blockIdx.x / NS, i = blockIdx.x % NS;
  const int t = threadIdx.x;
  const int e = t & 63, jg = t >> 6;
  __shared__ float red[4 * ND];
  __shared__ float phi1[ND];
  __shared__ float hid[NF];
  const float* Pb = P + (size_t)b * NS * NS * ND;
  float s = 0.f;
  #pragma unroll 4
  for (int m = 0; m < 32; ++m) {
    const int jj = jg * 32 + m;
    s += Pb[((size_t)jj * NS + i) * ND + e];
  }
  red[t] = s;
  __syncthreads();
  if (t < ND) {
    const float agg = red[e] + red[ND + e] + red[2 * ND + e] + red[3 * ND + e] +
                      bias_agg[b * ND + e];
    const float x = q[((size_t)b * NS + i) * ND + e] + agg;
    float sum = x, sumsq = x * x;
    #pragma unroll
    for (int off = 32; off >= 1; off >>= 1) {
      sum += __shfl_xor(sum, off);
      sumsq += __shfl_xor(sumsq, off);
    }
    const float mu = sum * (1.f / 64.f);
    const float var = sumsq * (1.f / 64.f) - mu * mu;
    const float inv = rsqrtf(var + 1e-5f);
    phi1[e] = (x - mu) * inv * ln1g[e] + ln1b[e];
  }
  __syncthreads();
  {
    float h = mb1[t];
    #pragma unroll 8
    for (int d = 0; d < ND; ++d) h += phi1[d] * mw1[d * NF + t];
    hid[t] = gelu_exact(h);
  }
  __syncthreads();
  {
    float p = 0.f;
    #pragma unroll 8
    for (int m = 0; m < 64; ++m) {
      const int f = jg * 64 + m;
      p += hid[f] * mw2[f * ND + e];
    }
    red[t] = p;
  }
  __syncthreads();
  if (t < ND) {
    const float mlp = red[e] + red[ND + e] + red[2 * ND + e] + red[3 * ND + e] + mb2[e];
    const float x = phi1[e] + mlp;
    float sum = x, sumsq = x * x;
    #pragma unroll
    for (int off = 32; off >= 1; off >>= 1) {
      sum += __shfl_xor(sum, off);
      sumsq += __shfl_xor(sumsq, off);
    }
    const float mu = sum * (1.f / 64.f);
    const float var = sumsq * (1.f / 64.f) - mu * mu;
    const float inv = rsqrtf(var + 1e-5f);
    out[((size_t)b * NS + i) * ND + e] = (x - mu) * inv * ln2g[e] + ln2b[e];
  }
}

}  // namespace

extern "C" void kernel_launch(void* const* d_in, const int* in_sizes, int n_in,
                              void* d_out, int out_size, void* d_ws, size_t ws_size,
                              hipStream_t stream) {
  const float* q    = (const float*)d_in[0];
  const float* gw1  = (const float*)d_in[1];
  const float* gb1  = (const float*)d_in[2];
  const float* gw2  = (const float*)d_in[3];
  const float* gb2  = (const float*)d_in[4];
  const float* mw1  = (const float*)d_in[5];
  const float* mb1  = (const float*)d_in[6];
  const float* mw2  = (const float*)d_in[7];
  const float* mb2  = (const float*)d_in[8];
  const float* ln1g = (const float*)d_in[9];
  const float* ln1b = (const float*)d_in[10];
  const float* ln2g = (const float*)d_in[11];
  const float* ln2b = (const float*)d_in[12];
  float* out = (float*)d_out;
  float* ws  = (float*)d_ws;

  float* W2   = ws + OFF_W2;
  float* Pp   = ws + OFF_P;
  float* A_t  = ws + OFF_AT;
  float* Bt   = ws + OFF_BT;
  float* q_t  = ws + OFF_QT;
  float* bias = ws + OFF_BIAS;

  k0_qt_bias<<<NB, 256, 0, stream>>>(q, gb2, q_t, bias);
  k1_pre<<<NB * NS + NB * NF, 256, 0, stream>>>(q, gw1, gb1, gw2, q_t, A_t, Bt, W2);
  k2_main<<<NB * NS, 256, 0, stream>>>(A_t, Bt, W2, Pp);
  k3_epi<<<NB * NS, 256, 0, stream>>>(q, Pp, bias, mw1, mb1, mw2, mb2,
                                      ln1g, ln1b, ln2g, ln2b, out);
}

// Round 2
// 124.725 us; speedup vs baseline: 1.1448x; 1.1448x over previous
//
#include <hip/hip_runtime.h>
#include <math.h>

namespace {

constexpr int NB = 2, NS = 128, ND = 64, NF = 256;

// workspace offsets (floats)
constexpr size_t OFF_W2   = 0;                               // [B][S(j)][F][D]
constexpr size_t SZ_W2    = (size_t)NB * NS * NF * ND;
constexpr size_t OFF_P    = OFF_W2 + SZ_W2;                  // [B][S(j)][S(i)][D]
constexpr size_t SZ_P     = (size_t)NB * NS * NS * ND;
constexpr size_t OFF_AT   = OFF_P + SZ_P;                    // [B][F][S(i)]
constexpr size_t SZ_AT    = (size_t)NB * NF * NS;
constexpr size_t OFF_BT   = OFF_AT + SZ_AT;                  // [B][S(j)][F] (+gb1)
constexpr size_t SZ_BT    = (size_t)NB * NS * NF;
constexpr size_t OFF_BIAS = OFF_BT + SZ_BT;                  // [B][D]

// A&S 7.1.26 erf: |err| <= 1.5e-7, branchless. ~14 VALU ops total.
__device__ __forceinline__ float gelu_fast(float x) {
  const float xs = fabsf(x) * 0.70710678118654752f;  // |x|/sqrt(2)
  const float t = __builtin_amdgcn_rcpf(fmaf(0.3275911f, xs, 1.0f));
  float p = fmaf(1.061405429f, t, -1.453152027f);
  p = fmaf(p, t, 1.421413741f);
  p = fmaf(p, t, -0.284496736f);
  p = fmaf(p, t, 0.254829592f);
  p *= t;
  const float e = __expf(-xs * xs);
  const float erf_ax = fmaf(-p, e, 1.0f);
  const float erf_x = copysignf(erf_ax, x);
  return 0.5f * x * (1.0f + erf_x);
}

// ---------------------------------------------------------------------------
// kA: blocks [0, B*S)            : A_t[b][f][i], Bt[b][j][f] (+gb1)
//     blocks [B*S, B*S+B*F)      : W2[b][j][f][e] = sum_d q[b][j][d]*gw2[f][d*D+e]
//     blocks [B*S+B*F, ...+B)    : bias_agg[b][e] = sum_d gb2[d*D+e]*sum_j q[b][j][d]
// ---------------------------------------------------------------------------
constexpr int QT_LD = NS + 4;  // 132: pad so transpose writes are 8-way not 64-way

__global__ __launch_bounds__(256) void kA_pre(const float* __restrict__ q,
                                              const float* __restrict__ gw1,
                                              const float* __restrict__ gb1,
                                              const float* __restrict__ gw2,
                                              const float* __restrict__ gb2,
                                              float* __restrict__ A_t,
                                              float* __restrict__ Bt,
                                              float* __restrict__ W2,
                                              float* __restrict__ bias_agg) {
  __shared__ __align__(16) float smem[ND * QT_LD + ND * ND];  // 12544 floats
  const int t = threadIdx.x;
  const int bid = blockIdx.x;
  if (bid < NB * NS) {
    // ---- A / Bt ----
    const int b = bid / NS, i = bid % NS;
    float* qrow = smem;
    if (t < ND) qrow[t] = q[((size_t)b * NS + i) * ND + t];
    __syncthreads();
    const int f = t;  // 256 threads == F
    float a = 0.f, bb = gb1[f];
    #pragma unroll 8
    for (int d = 0; d < ND; ++d) {
      const float qd = qrow[d];
      a  += qd * gw1[d * NF + f];
      bb += qd * gw1[(ND + d) * NF + f];
    }
    A_t[((size_t)b * NF + f) * NS + i] = a;
    Bt[((size_t)b * NS + i) * NF + f] = bb;
  } else if (bid < NB * NS + NB * NF) {
    // ---- W2phi ----
    const int idx = bid - NB * NS;
    const int b = idx / NF, f = idx % NF;
    float* qt = smem;                 // [d][j], row stride QT_LD
    float* G  = smem + ND * QT_LD;    // gw2 row f, [d][e]
    for (int r = 0; r < ND * ND / 256; ++r)
      G[t + r * 256] = gw2[(size_t)f * ND * ND + t + r * 256];
    // transpose q[b] into qt (coalesced reads; 8-way-conflict LDS writes, 32 insts)
    const float* qb = q + (size_t)b * NS * ND;
    for (int r = 0; r < NS * ND / 256; ++r) {
      const int lin = t + r * 256;
      const int j = lin >> 6, d = lin & 63;
      qt[d * QT_LD + j] = qb[lin];
    }
    __syncthreads();
    const int tj = t >> 3, te = t & 7;   // 32 x 8 thread grid
    const int j0 = tj * 4, e0 = te * 8;  // 4j x 8e register tile
    float acc[4][8];
    #pragma unroll
    for (int jj = 0; jj < 4; ++jj)
      #pragma unroll
      for (int ee = 0; ee < 8; ++ee) acc[jj][ee] = 0.f;
    #pragma unroll 4
    for (int d = 0; d < ND; ++d) {
      const float4 qv = *(const float4*)&qt[d * QT_LD + j0];
      const float4 g0 = *(const float4*)&G[d * ND + e0];
      const float4 g1 = *(const float4*)&G[d * ND + e0 + 4];
      const float qa[4] = {qv.x, qv.y, qv.z, qv.w};
      const float ga[8] = {g0.x, g0.y, g0.z, g0.w, g1.x, g1.y, g1.z, g1.w};
      #pragma unroll
      for (int jj = 0; jj < 4; ++jj)
        #pragma unroll
        for (int ee = 0; ee < 8; ++ee) acc[jj][ee] += qa[jj] * ga[ee];
    }
    #pragma unroll
    for (int jj = 0; jj < 4; ++jj) {
      const int j = j0 + jj;
      float* dst = W2 + (((size_t)b * NS + j) * NF + f) * ND + e0;
      *(float4*)&dst[0] = make_float4(acc[jj][0], acc[jj][1], acc[jj][2], acc[jj][3]);
      *(float4*)&dst[4] = make_float4(acc[jj][4], acc[jj][5], acc[jj][6], acc[jj][7]);
    }
  } else {
    // ---- bias_agg ----
    const int b = bid - (NB * NS + NB * NF);
    float* qs = smem;            // [j][d]
    float* colsum = smem + NS * ND;
    const float* qb = q + (size_t)b * NS * ND;
    for (int r = 0; r < NS * ND / 256; ++r) qs[t + r * 256] = qb[t + r * 256];
    __syncthreads();
    if (t < ND) {
      float s = 0.f;
      for (int j = 0; j < NS; ++j) s += qs[j * ND + t];
      colsum[t] = s;
    }
    __syncthreads();
    if (t < ND) {
      float acc = 0.f;
      for (int d = 0; d < ND; ++d) acc += gb2[d * ND + t] * colsum[d];
      bias_agg[b * ND + t] = acc;
    }
  }
}

// ---------------------------------------------------------------------------
// k2: one wg (512 thr) per (b,j):
//   P[b][j][i][e] = sum_f gelu(A_t[b][f][i]+Bt[b][j][f]) * W2[b][j][f][e]
// Software pipeline: Wc chunk c+1 prefetched into registers during GEMM of c.
// ---------------------------------------------------------------------------
__global__ __launch_bounds__(512) void k2_main(const float* __restrict__ A_t,
                                               const float* __restrict__ Bt,
                                               const float* __restrict__ W2,
                                               float* __restrict__ P) {
  const int b = blockIdx.x / NS, j = blockIdx.x % NS;
  const int t = threadIdx.x;
  __shared__ float Btj[NF];
  __shared__ __align__(16) float Hc[64 * NS];  // [fc][i]  32 KB
  __shared__ __align__(16) float Wc[64 * ND];  // [fc][e]  16 KB
  if (t < NF) Btj[t] = Bt[((size_t)b * NS + j) * NF + t];
  const float* W2bj = W2 + ((size_t)b * NS + j) * NF * ND;
  const float* Ab = A_t + (size_t)b * NF * NS;

  const int ty = t >> 4, tx = t & 15;  // 32 x 16
  const int i0 = ty * 4, e0 = tx * 4;  // 4i x 4e register tile
  const int ih = t & 127, fh = (t >> 7) * 16;
  float acc[4][4];
  #pragma unroll
  for (int r = 0; r < 4; ++r)
    #pragma unroll
    for (int cc = 0; cc < 4; ++cc) acc[r][cc] = 0.f;

  // prefetch chunk 0 (8 floats/thread)
  float4 w0 = *(const float4*)&W2bj[t * 8];
  float4 w1 = *(const float4*)&W2bj[t * 8 + 4];

  for (int c = 0; c < NF / 64; ++c) {
    __syncthreads();  // previous chunk's LDS fully consumed
    *(float4*)&Wc[t * 8]     = w0;
    *(float4*)&Wc[t * 8 + 4] = w1;
    #pragma unroll 4
    for (int m = 0; m < 16; ++m) {
      const int fc = fh + m;
      const float v = Ab[(c * 64 + fc) * NS + ih] + Btj[c * 64 + fc];
      Hc[fc * NS + ih] = gelu_fast(v);
    }
    if (c < NF / 64 - 1) {  // issue next chunk's loads; consumed after next barrier
      w0 = *(const float4*)&W2bj[(c + 1) * 64 * ND + t * 8];
      w1 = *(const float4*)&W2bj[(c + 1) * 64 * ND + t * 8 + 4];
    }
    __syncthreads();
    #pragma unroll 4
    for (int fc = 0; fc < 64; ++fc) {
      const float4 h = *(const float4*)&Hc[fc * NS + i0];
      const float4 w = *(const float4*)&Wc[fc * ND + e0];
      const float ha[4] = {h.x, h.y, h.z, h.w};
      const float wa[4] = {w.x, w.y, w.z, w.w};
      #pragma unroll
      for (int r = 0; r < 4; ++r)
        #pragma unroll
        for (int cc = 0; cc < 4; ++cc) acc[r][cc] += ha[r] * wa[cc];
    }
  }
  float* Pbj = P + ((size_t)b * NS + j) * NS * ND;
  #pragma unroll
  for (int r = 0; r < 4; ++r) {
    *(float4*)&Pbj[(size_t)(i0 + r) * ND + e0] =
        make_float4(acc[r][0], acc[r][1], acc[r][2], acc[r][3]);
  }
}

// ---------------------------------------------------------------------------
// k3: one wg (512 thr) per (b,i): agg-reduce over j, LN1, MLP, LN2 -> out
// ---------------------------------------------------------------------------
__global__ __launch_bounds__(512) void k3_epi(const float* __restrict__ q,
                                              const float* __restrict__ P,
                                              const float* __restrict__ bias_agg,
                                              const float* __restrict__ mw1,
                                              const float* __restrict__ mb1,
                                              const float* __restrict__ mw2,
                                              const float* __restrict__ mb2,
                                              const float* __restrict__ ln1g,
                                              const float* __restrict__ ln1b,
                                              const float* __restrict__ ln2g,
                                              const float* __restrict__ ln2b,
                                              float* __restrict__ out) {
  const int b = blockIdx.x / NS, i = blockIdx.x % NS;
  const int t = threadIdx.x;
  const int e = t & 63, g = t >> 6;  // 8 j/f groups
  __shared__ float red[8 * ND];
  __shared__ float phi1[ND];
  __shared__ float hid[NF];
  const float* Pb = P + (size_t)b * NS * NS * ND;
  float s = 0.f;
  #pragma unroll 4
  for (int m = 0; m < 16; ++m) {
    const int jj = g * 16 + m;
    s += Pb[((size_t)jj * NS + i) * ND + e];
  }
  red[t] = s;
  __syncthreads();
  if (t < ND) {
    float agg = bias_agg[b * ND + e];
    #pragma unroll
    for (int gg = 0; gg < 8; ++gg) agg += red[gg * ND + e];
    const float x = q[((size_t)b * NS + i) * ND + e] + agg;
    float sum = x, sumsq = x * x;
    #pragma unroll
    for (int off = 32; off >= 1; off >>= 1) {
      sum += __shfl_xor(sum, off);
      sumsq += __shfl_xor(sumsq, off);
    }
    const float mu = sum * (1.f / 64.f);
    const float var = sumsq * (1.f / 64.f) - mu * mu;
    const float inv = rsqrtf(var + 1e-5f);
    phi1[e] = (x - mu) * inv * ln1g[e] + ln1b[e];
  }
  __syncthreads();
  if (t < NF) {
    float h = mb1[t];
    #pragma unroll 8
    for (int d = 0; d < ND; ++d) h += phi1[d] * mw1[d * NF + t];
    hid[t] = gelu_fast(h);
  }
  __syncthreads();
  {
    float p = 0.f;
    #pragma unroll 8
    for (int m = 0; m < 32; ++m) {
      const int f = g * 32 + m;
      p += hid[f] * mw2[f * ND + e];
    }
    red[t] = p;
  }
  __syncthreads();
  if (t < ND) {
    float mlp = mb2[e];
    #pragma unroll
    for (int gg = 0; gg < 8; ++gg) mlp += red[gg * ND + e];
    const float x = phi1[e] + mlp;
    float sum = x, sumsq = x * x;
    #pragma unroll
    for (int off = 32; off >= 1; off >>= 1) {
      sum += __shfl_xor(sum, off);
      sumsq += __shfl_xor(sumsq, off);
    }
    const float mu = sum * (1.f / 64.f);
    const float var = sumsq * (1.f / 64.f) - mu * mu;
    const float inv = rsqrtf(var + 1e-5f);
    out[((size_t)b * NS + i) * ND + e] = (x - mu) * inv * ln2g[e] + ln2b[e];
  }
}

}  // namespace

extern "C" void kernel_launch(void* const* d_in, const int* in_sizes, int n_in,
                              void* d_out, int out_size, void* d_ws, size_t ws_size,
                              hipStream_t stream) {
  const float* q    = (const float*)d_in[0];
  const float* gw1  = (const float*)d_in[1];
  const float* gb1  = (const float*)d_in[2];
  const float* gw2  = (const float*)d_in[3];
  const float* gb2  = (const float*)d_in[4];
  const float* mw1  = (const float*)d_in[5];
  const float* mb1  = (const float*)d_in[6];
  const float* mw2  = (const float*)d_in[7];
  const float* mb2  = (const float*)d_in[8];
  const float* ln1g = (const float*)d_in[9];
  const float* ln1b = (const float*)d_in[10];
  const float* ln2g = (const float*)d_in[11];
  const float* ln2b = (const float*)d_in[12];
  float* out = (float*)d_out;
  float* ws  = (float*)d_ws;

  float* W2   = ws + OFF_W2;
  float* Pp   = ws + OFF_P;
  float* A_t  = ws + OFF_AT;
  float* Bt   = ws + OFF_BT;
  float* bias = ws + OFF_BIAS;

  kA_pre<<<NB * NS + NB * NF + NB, 256, 0, stream>>>(q, gw1, gb1, gw2, gb2,
                                                     A_t, Bt, W2, bias);
  k2_main<<<NB * NS, 512, 0, stream>>>(A_t, Bt, W2, Pp);
  k3_epi<<<NB * NS, 512, 0, stream>>>(q, Pp, bias, mw1, mb1, mw2, mb2,
                                      ln1g, ln1b, ln2g, ln2b, out);
}

// Round 3
// 112.896 us; speedup vs baseline: 1.2648x; 1.1048x over previous
//
#include <hip/hip_runtime.h>
#include <hip/hip_bf16.h>
#include <math.h>

namespace {

constexpr int NB = 2, NS = 128, ND = 64, NF = 256;

typedef __attribute__((ext_vector_type(8))) short short8;
typedef __attribute__((ext_vector_type(8))) unsigned short ushort8;
typedef __attribute__((ext_vector_type(4))) float floatx4;

// workspace offsets (floats)
constexpr size_t OFF_W2   = 0;                               // [B][S(j)][F][D] fp32
constexpr size_t SZ_W2    = (size_t)NB * NS * NF * ND;
constexpr size_t OFF_P    = OFF_W2 + SZ_W2;                  // [B][S(j)][S(i)][D] fp32
constexpr size_t SZ_P     = (size_t)NB * NS * NS * ND;
constexpr size_t OFF_AT   = OFF_P + SZ_P;                    // [B][F][S(i)]
constexpr size_t SZ_AT    = (size_t)NB * NF * NS;
constexpr size_t OFF_BT   = OFF_AT + SZ_AT;                  // [B][S(j)][F] (+gb1)
constexpr size_t SZ_BT    = (size_t)NB * NS * NF;
constexpr size_t OFF_BIAS = OFF_BT + SZ_BT;                  // [B][D]

// A&S 7.1.26 erf: |err| <= 1.5e-7, branchless.
__device__ __forceinline__ float gelu_fast(float x) {
  const float xs = fabsf(x) * 0.70710678118654752f;
  const float t = __builtin_amdgcn_rcpf(fmaf(0.3275911f, xs, 1.0f));
  float p = fmaf(1.061405429f, t, -1.453152027f);
  p = fmaf(p, t, 1.421413741f);
  p = fmaf(p, t, -0.284496736f);
  p = fmaf(p, t, 0.254829592f);
  p *= t;
  const float e = __expf(-xs * xs);
  const float erf_ax = fmaf(-p, e, 1.0f);
  const float erf_x = copysignf(erf_ax, x);
  return 0.5f * x * (1.0f + erf_x);
}

// ---------------------------------------------------------------------------
// kA: blocks [0, B*S)            : A_t[b][f][i], Bt[b][j][f] (+gb1)
//     blocks [B*S, B*S+B*F)      : W2[b][j][f][e] = sum_d q[b][j][d]*gw2[f][d*D+e]
//     blocks [B*S+B*F, ...+B)    : bias_agg[b][e] = sum_d gb2[d*D+e]*sum_j q[b][j][d]
// ---------------------------------------------------------------------------
constexpr int QT_LD = NS + 4;  // 132: pad so transpose writes are 8-way not 64-way

__global__ __launch_bounds__(256) void kA_pre(const float* __restrict__ q,
                                              const float* __restrict__ gw1,
                                              const float* __restrict__ gb1,
                                              const float* __restrict__ gw2,
                                              const float* __restrict__ gb2,
                                              float* __restrict__ A_t,
                                              float* __restrict__ Bt,
                                              float* __restrict__ W2,
                                              float* __restrict__ bias_agg) {
  __shared__ __align__(16) float smem[ND * QT_LD + ND * ND];
  const int t = threadIdx.x;
  const int bid = blockIdx.x;
  if (bid < NB * NS) {
    const int b = bid / NS, i = bid % NS;
    float* qrow = smem;
    if (t < ND) qrow[t] = q[((size_t)b * NS + i) * ND + t];
    __syncthreads();
    const int f = t;
    float a = 0.f, bb = gb1[f];
    #pragma unroll 8
    for (int d = 0; d < ND; ++d) {
      const float qd = qrow[d];
      a  += qd * gw1[d * NF + f];
      bb += qd * gw1[(ND + d) * NF + f];
    }
    A_t[((size_t)b * NF + f) * NS + i] = a;
    Bt[((size_t)b * NS + i) * NF + f] = bb;
  } else if (bid < NB * NS + NB * NF) {
    const int idx = bid - NB * NS;
    const int b = idx / NF, f = idx % NF;
    float* qt = smem;                 // [d][j], row stride QT_LD
    float* G  = smem + ND * QT_LD;    // gw2 row f, [d][e]
    for (int r = 0; r < ND * ND / 256; ++r)
      G[t + r * 256] = gw2[(size_t)f * ND * ND + t + r * 256];
    const float* qb = q + (size_t)b * NS * ND;
    for (int r = 0; r < NS * ND / 256; ++r) {
      const int lin = t + r * 256;
      const int j = lin >> 6, d = lin & 63;
      qt[d * QT_LD + j] = qb[lin];
    }
    __syncthreads();
    const int tj = t >> 3, te = t & 7;
    const int j0 = tj * 4, e0 = te * 8;
    float acc[4][8];
    #pragma unroll
    for (int jj = 0; jj < 4; ++jj)
      #pragma unroll
      for (int ee = 0; ee < 8; ++ee) acc[jj][ee] = 0.f;
    #pragma unroll 4
    for (int d = 0; d < ND; ++d) {
      const float4 qv = *(const float4*)&qt[d * QT_LD + j0];
      const float4 g0 = *(const float4*)&G[d * ND + e0];
      const float4 g1 = *(const float4*)&G[d * ND + e0 + 4];
      const float qa[4] = {qv.x, qv.y, qv.z, qv.w};
      const float ga[8] = {g0.x, g0.y, g0.z, g0.w, g1.x, g1.y, g1.z, g1.w};
      #pragma unroll
      for (int jj = 0; jj < 4; ++jj)
        #pragma unroll
        for (int ee = 0; ee < 8; ++ee) acc[jj][ee] += qa[jj] * ga[ee];
    }
    #pragma unroll
    for (int jj = 0; jj < 4; ++jj) {
      const int j = j0 + jj;
      float* dst = W2 + (((size_t)b * NS + j) * NF + f) * ND + e0;
      *(float4*)&dst[0] = make_float4(acc[jj][0], acc[jj][1], acc[jj][2], acc[jj][3]);
      *(float4*)&dst[4] = make_float4(acc[jj][4], acc[jj][5], acc[jj][6], acc[jj][7]);
    }
  } else {
    const int b = bid - (NB * NS + NB * NF);
    float* qs = smem;
    float* colsum = smem + NS * ND;
    const float* qb = q + (size_t)b * NS * ND;
    for (int r = 0; r < NS * ND / 256; ++r) qs[t + r * 256] = qb[t + r * 256];
    __syncthreads();
    if (t < ND) {
      float s = 0.f;
      for (int j = 0; j < NS; ++j) s += qs[j * ND + t];
      colsum[t] = s;
    }
    __syncthreads();
    if (t < ND) {
      float acc = 0.f;
      for (int d = 0; d < ND; ++d) acc += gb2[d * ND + t] * colsum[d];
      bias_agg[b * ND + t] = acc;
    }
  }
}

// ---------------------------------------------------------------------------
// k2: one wg (512 thr, 8 waves) per (b,j). MFMA bf16 16x16x32, fp32 accum.
//   P[i][e] = sum_f gelu(A_t[f][i]+Btj[f]) * W2[f][e],  M=128,N=64,K=256
// LDS: Hc[i][f] bf16 (stride 72), WcT[e][f] bf16 (stride 72) — B-operand
// transposed at staging time from strided-coalesced global dword loads.
// ---------------------------------------------------------------------------
constexpr int HLD = 72;  // ushort stride: 144 B -> bank step 4, conflict-free b128

__global__ __launch_bounds__(512) void k2_main(const float* __restrict__ A_t,
                                               const float* __restrict__ Bt,
                                               const float* __restrict__ W2,
                                               float* __restrict__ P) {
  const int b = blockIdx.x / NS, j = blockIdx.x % NS;
  const int t = threadIdx.x;
  const int lane = t & 63, w = t >> 6;
  __shared__ float Btj[NF];
  __shared__ __align__(16) unsigned short Hc[NS * HLD];  // 18432 B
  __shared__ __align__(16) unsigned short Wc[ND * HLD];  //  9216 B
  if (t < NF) Btj[t] = Bt[((size_t)b * NS + j) * NF + t];

  const float* W2bj = W2 + ((size_t)b * NS + j) * NF * ND;
  const float* Ab = A_t + (size_t)b * NF * NS;

  // wave tile: 4 i-groups x 2 e-groups of 32x32
  const int wi = (w & 3) * 32, we = (w >> 2) * 32;
  const int m = lane & 15, quad = lane >> 4;

  // staging roles
  const int hi = (w & 1) * 64 + lane;  // H: i index (same for both octs)
  const int hoct0 = t >> 7;            // H: f-oct 0..3 (second task: +4)
  const int weid = t & 63, woct = t >> 6;  // W: e index, f-oct 0..7

  floatx4 acc[2][2];
  #pragma unroll
  for (int a0 = 0; a0 < 2; ++a0)
    #pragma unroll
    for (int a1 = 0; a1 < 2; ++a1) acc[a0][a1] = (floatx4)0.f;

  for (int c = 0; c < NF / 64; ++c) {
    __syncthreads();
    // ---- stage W chunk: Wc[e][fc] = bf16(W2[c*64+fc][e]) ----
    float wv[8];
    #pragma unroll
    for (int r = 0; r < 8; ++r)
      wv[r] = W2bj[(size_t)(c * 64 + woct * 8 + r) * ND + weid];
    // ---- stage H chunk: Hc[i][fc] = bf16(gelu(A_t[f][i]+Btj[f])) ----
    float hv[2][8];
    #pragma unroll
    for (int s = 0; s < 2; ++s) {
      const int oct = hoct0 + 4 * s;
      #pragma unroll
      for (int r = 0; r < 8; ++r) {
        const int f = c * 64 + oct * 8 + r;
        hv[s][r] = gelu_fast(Ab[(size_t)f * NS + hi] + Btj[f]);
      }
    }
    {
      union { __hip_bfloat162 b2[4]; ushort8 v; } u;
      #pragma unroll
      for (int p = 0; p < 4; ++p)
        u.b2[p] = __float22bfloat162_rn(make_float2(wv[2 * p], wv[2 * p + 1]));
      *(ushort8*)&Wc[weid * HLD + woct * 8] = u.v;
    }
    #pragma unroll
    for (int s = 0; s < 2; ++s) {
      union { __hip_bfloat162 b2[4]; ushort8 v; } u;
      #pragma unroll
      for (int p = 0; p < 4; ++p)
        u.b2[p] = __float22bfloat162_rn(make_float2(hv[s][2 * p], hv[s][2 * p + 1]));
      *(ushort8*)&Hc[hi * HLD + (hoct0 + 4 * s) * 8] = u.v;
    }
    __syncthreads();
    // ---- MFMA: 2 k-tiles of 32 per chunk ----
    #pragma unroll
    for (int kk = 0; kk < 2; ++kk) {
      short8 afr[2], bfr[2];
      #pragma unroll
      for (int ti = 0; ti < 2; ++ti)
        afr[ti] = *(const short8*)&Hc[(wi + ti * 16 + m) * HLD + kk * 32 + quad * 8];
      #pragma unroll
      for (int te = 0; te < 2; ++te)
        bfr[te] = *(const short8*)&Wc[(we + te * 16 + m) * HLD + kk * 32 + quad * 8];
      #pragma unroll
      for (int ti = 0; ti < 2; ++ti)
        #pragma unroll
        for (int te = 0; te < 2; ++te)
          acc[ti][te] = __builtin_amdgcn_mfma_f32_16x16x32_bf16(
              afr[ti], bfr[te], acc[ti][te], 0, 0, 0);
    }
  }
  // ---- epilogue: D layout row=(lane>>4)*4+reg, col=lane&15 ----
  float* Pbj = P + ((size_t)b * NS + j) * NS * ND;
  #pragma unroll
  for (int ti = 0; ti < 2; ++ti)
    #pragma unroll
    for (int te = 0; te < 2; ++te)
      #pragma unroll
      for (int r = 0; r < 4; ++r) {
        const int row = wi + ti * 16 + quad * 4 + r;
        const int col = we + te * 16 + m;
        Pbj[(size_t)row * ND + col] = acc[ti][te][r];
      }
}

// ---------------------------------------------------------------------------
// k3: one wg (512 thr) per (b,i): agg-reduce over j, LN1, MLP, LN2 -> out
// ---------------------------------------------------------------------------
__global__ __launch_bounds__(512) void k3_epi(const float* __restrict__ q,
                                              const float* __restrict__ P,
                                              const float* __restrict__ bias_agg,
                                              const float* __restrict__ mw1,
                                              const float* __restrict__ mb1,
                                              const float* __restrict__ mw2,
                                              const float* __restrict__ mb2,
                                              const float* __restrict__ ln1g,
                                              const float* __restrict__ ln1b,
                                              const float* __restrict__ ln2g,
                                              const float* __restrict__ ln2b,
                                              float* __restrict__ out) {
  const int b = blockIdx.x / NS, i = blockIdx.x % NS;
  const int t = threadIdx.x;
  const int e = t & 63, g = t >> 6;
  __shared__ float red[8 * ND];
  __shared__ float phi1[ND];
  __shared__ float hid[NF];
  const float* Pb = P + (size_t)b * NS * NS * ND;
  float s = 0.f;
  #pragma unroll 4
  for (int m0 = 0; m0 < 16; ++m0) {
    const int jj = g * 16 + m0;
    s += Pb[((size_t)jj * NS + i) * ND + e];
  }
  red[t] = s;
  __syncthreads();
  if (t < ND) {
    float agg = bias_agg[b * ND + e];
    #pragma unroll
    for (int gg = 0; gg < 8; ++gg) agg += red[gg * ND + e];
    const float x = q[((size_t)b * NS + i) * ND + e] + agg;
    float sum = x, sumsq = x * x;
    #pragma unroll
    for (int off = 32; off >= 1; off >>= 1) {
      sum += __shfl_xor(sum, off);
      sumsq += __shfl_xor(sumsq, off);
    }
    const float mu = sum * (1.f / 64.f);
    const float var = sumsq * (1.f / 64.f) - mu * mu;
    const float inv = rsqrtf(var + 1e-5f);
    phi1[e] = (x - mu) * inv * ln1g[e] + ln1b[e];
  }
  __syncthreads();
  if (t < NF) {
    float h = mb1[t];
    #pragma unroll 8
    for (int d = 0; d < ND; ++d) h += phi1[d] * mw1[d * NF + t];
    hid[t] = gelu_fast(h);
  }
  __syncthreads();
  {
    float p = 0.f;
    #pragma unroll 8
    for (int m0 = 0; m0 < 32; ++m0) {
      const int f = g * 32 + m0;
      p += hid[f] * mw2[f * ND + e];
    }
    red[t] = p;
  }
  __syncthreads();
  if (t < ND) {
    float mlp = mb2[e];
    #pragma unroll
    for (int gg = 0; gg < 8; ++gg) mlp += red[gg * ND + e];
    const float x = phi1[e] + mlp;
    float sum = x, sumsq = x * x;
    #pragma unroll
    for (int off = 32; off >= 1; off >>= 1) {
      sum += __shfl_xor(sum, off);
      sumsq += __shfl_xor(sumsq, off);
    }
    const float mu = sum * (1.f / 64.f);
    const float var = sumsq * (1.f / 64.f) - mu * mu;
    const float inv = rsqrtf(var + 1e-5f);
    out[((size_t)b * NS + i) * ND + e] = (x - mu) * inv * ln2g[e] + ln2b[e];
  }
}

}  // namespace

extern "C" void kernel_launch(void* const* d_in, const int* in_sizes, int n_in,
                              void* d_out, int out_size, void* d_ws, size_t ws_size,
                              hipStream_t stream) {
  const float* q    = (const float*)d_in[0];
  const float* gw1  = (const float*)d_in[1];
  const float* gb1  = (const float*)d_in[2];
  const float* gw2  = (const float*)d_in[3];
  const float* gb2  = (const float*)d_in[4];
  const float* mw1  = (const float*)d_in[5];
  const float* mb1  = (const float*)d_in[6];
  const float* mw2  = (const float*)d_in[7];
  const float* mb2  = (const float*)d_in[8];
  const float* ln1g = (const float*)d_in[9];
  const float* ln1b = (const float*)d_in[10];
  const float* ln2g = (const float*)d_in[11];
  const float* ln2b = (const float*)d_in[12];
  float* out = (float*)d_out;
  float* ws  = (float*)d_ws;

  float* W2   = ws + OFF_W2;
  float* Pp   = ws + OFF_P;
  float* A_t  = ws + OFF_AT;
  float* Bt   = ws + OFF_BT;
  float* bias = ws + OFF_BIAS;

  kA_pre<<<NB * NS + NB * NF + NB, 256, 0, stream>>>(q, gw1, gb1, gw2, gb2,
                                                     A_t, Bt, W2, bias);
  k2_main<<<NB * NS, 512, 0, stream>>>(A_t, Bt, W2, Pp);
  k3_epi<<<NB * NS, 512, 0, stream>>>(q, Pp, bias, mw1, mb1, mw2, mb2,
                                      ln1g, ln1b, ln2g, ln2b, out);
}

// Round 4
// 109.439 us; speedup vs baseline: 1.3047x; 1.0316x over previous
//
#include <hip/hip_runtime.h>
#include <hip/hip_bf16.h>
#include <math.h>

namespace {

constexpr int NB = 2, NS = 128, ND = 64, NF = 256;

typedef __attribute__((ext_vector_type(8))) short short8;
typedef __attribute__((ext_vector_type(8))) unsigned short ushort8;
typedef __attribute__((ext_vector_type(4))) float floatx4;

// workspace offsets (float units)
constexpr size_t OFF_W2H  = 0;                                   // [B][S(j)][F][D] bf16
constexpr size_t SZ_W2H   = (size_t)NB * NS * NF * ND / 2;       // ushorts stored in float space
constexpr size_t OFF_P    = OFF_W2H + SZ_W2H;                    // [B][S(j)][S(i)][D] fp32
constexpr size_t SZ_P     = (size_t)NB * NS * NS * ND;
constexpr size_t OFF_AT   = OFF_P + SZ_P;                        // [B][F][S(i)] fp32
constexpr size_t SZ_AT    = (size_t)NB * NF * NS;
constexpr size_t OFF_BT   = OFF_AT + SZ_AT;                      // [B][S(j)][F] fp32 (+gb1)
constexpr size_t SZ_BT    = (size_t)NB * NS * NF;
constexpr size_t OFF_BIAS = OFF_BT + SZ_BT;                      // [B][D]

// A&S 7.1.26 erf: |err| <= 1.5e-7, branchless.
__device__ __forceinline__ float gelu_fast(float x) {
  const float xs = fabsf(x) * 0.70710678118654752f;
  const float t = __builtin_amdgcn_rcpf(fmaf(0.3275911f, xs, 1.0f));
  float p = fmaf(1.061405429f, t, -1.453152027f);
  p = fmaf(p, t, 1.421413741f);
  p = fmaf(p, t, -0.284496736f);
  p = fmaf(p, t, 0.254829592f);
  p *= t;
  const float e = __expf(-xs * xs);
  const float erf_ax = fmaf(-p, e, 1.0f);
  const float erf_x = copysignf(erf_ax, x);
  return 0.5f * x * (1.0f + erf_x);
}

__device__ __forceinline__ ushort8 pack_bf16x8(const float v[8]) {
  union { __hip_bfloat162 b2[4]; ushort8 u; } u;
  #pragma unroll
  for (int p = 0; p < 4; ++p)
    u.b2[p] = __float22bfloat162_rn(make_float2(v[2 * p], v[2 * p + 1]));
  return u.u;
}

// ---------------------------------------------------------------------------
// kA (512 thr): blocks [0,128)   : A_t / Bt  (2 i's per block)
//               blocks [128,192) : W2h[b][j][f][e] bf16 via MFMA (8 f's/block, 1 f/wave)
//               blocks [192,194) : bias_agg[b][e]
// ---------------------------------------------------------------------------
__global__ __launch_bounds__(512) void kA_pre(const float* __restrict__ q,
                                              const float* __restrict__ gw1,
                                              const float* __restrict__ gb1,
                                              const float* __restrict__ gw2,
                                              const float* __restrict__ gb2,
                                              float* __restrict__ A_t,
                                              float* __restrict__ Bt,
                                              unsigned short* __restrict__ W2h,
                                              float* __restrict__ bias_agg) {
  __shared__ __align__(16) unsigned short smem_u[128 * 64 + 8 * 64 * 40];  // 57344 B
  float* smf = (float*)smem_u;
  const int t = threadIdx.x, bid = blockIdx.x;

  if (bid < 128) {
    // ---- A_t / Bt ----
    const int b = bid >> 6, ip = bid & 63;
    const int half = t >> 8, f = t & 255;
    const int i = ip * 2 + half;
    float* qrow = smf;  // [2][64]
    if (f < 64) qrow[half * 64 + f] = q[((size_t)b * NS + i) * ND + f];
    __syncthreads();
    float a = 0.f, bb = gb1[f];
    #pragma unroll 8
    for (int d = 0; d < ND; ++d) {
      const float qd = qrow[half * 64 + d];
      a  += qd * gw1[d * NF + f];
      bb += qd * gw1[(ND + d) * NF + f];
    }
    A_t[((size_t)b * NF + f) * NS + i] = a;
    Bt[((size_t)b * NS + i) * NF + f] = bb;
  } else if (bid < 192) {
    // ---- W2h via MFMA: W2[b][j][f][e] = sum_d q[b][j][d] * gw2[f][d*64+e] ----
    const int idx = bid - 128;
    const int b = idx >> 5, f0 = (idx & 31) * 8;
    unsigned short* qbf = smem_u;             // [j][64] bf16, oct xor-swizzled by (j&7)
    unsigned short* Gt  = smem_u + 128 * 64;  // [f'][e][40] bf16 (d-contig, pad 40)
    // stage qbf once: thread t -> (j = t>>1, half = t&1) covers 32 floats
    {
      const int jq = t >> 1, half = t & 1;
      const float* src = q + ((size_t)b * NS + jq) * ND + half * 32;
      #pragma unroll
      for (int p = 0; p < 4; ++p) {
        float v[8];
        #pragma unroll
        for (int r = 0; r < 8; ++r) v[r] = src[p * 8 + r];
        const int oct = half * 4 + p;
        const int col = oct ^ (jq & 7);
        *(ushort8*)&qbf[jq * 64 + col * 8] = pack_bf16x8(v);
      }
    }
    const int lane = t & 63, w = t >> 6;  // wave w handles f = f0 + w
    const int f = f0 + w;
    const int m = lane & 15, quad = lane >> 4;
    const int te = t & 63, tf = t >> 6;   // Gt staging roles
    floatx4 acc[8][4];
    #pragma unroll
    for (int ti = 0; ti < 8; ++ti)
      #pragma unroll
      for (int tn = 0; tn < 4; ++tn) acc[ti][tn] = (floatx4)0.f;

    for (int dc = 0; dc < 2; ++dc) {
      __syncthreads();  // qbf visible (dc=0) / prev MFMA reads done (dc=1)
      // stage Gt chunk: Gt[tf][te][d'] = bf16(gw2[f0+tf][(dc*32+d')*64 + te])
      const float* gsrc = gw2 + (size_t)(f0 + tf) * (ND * ND) + (size_t)(dc * 32) * ND + te;
      #pragma unroll
      for (int p = 0; p < 4; ++p) {
        float gv[8];
        #pragma unroll
        for (int r = 0; r < 8; ++r) gv[r] = gsrc[(size_t)(p * 8 + r) * ND];
        *(ushort8*)&Gt[tf * 2560 + te * 40 + p * 8] = pack_bf16x8(gv);
      }
      __syncthreads();
      // MFMA: one K=32 step per chunk; A = qbf[j][d], B^T = Gt[e][d]
      short8 bfr[4];
      #pragma unroll
      for (int tn = 0; tn < 4; ++tn)
        bfr[tn] = *(const short8*)&Gt[w * 2560 + (tn * 16 + m) * 40 + quad * 8];
      #pragma unroll
      for (int ti = 0; ti < 8; ++ti) {
        const int jr = ti * 16 + m;
        const int col = (dc * 4 + quad) ^ (jr & 7);
        const short8 afr = *(const short8*)&qbf[jr * 64 + col * 8];
        #pragma unroll
        for (int tn = 0; tn < 4; ++tn)
          acc[ti][tn] = __builtin_amdgcn_mfma_f32_16x16x32_bf16(afr, bfr[tn],
                                                                acc[ti][tn], 0, 0, 0);
      }
    }
    // epilogue: row j = ti*16 + quad*4 + r, col e = tn*16 + m -> W2h[b][j][f][e]
    __hip_bfloat16* Wh = (__hip_bfloat16*)W2h;
    #pragma unroll
    for (int ti = 0; ti < 8; ++ti)
      #pragma unroll
      for (int r = 0; r < 4; ++r) {
        const int jr = ti * 16 + quad * 4 + r;
        __hip_bfloat16* dst = Wh + ((size_t)(b * NS + jr) * NF + f) * ND;
        #pragma unroll
        for (int tn = 0; tn < 4; ++tn)
          dst[tn * 16 + m] = __float2bfloat16(acc[ti][tn][r]);
      }
  } else {
    // ---- bias_agg ----
    const int b = bid - 192;
    float* qs = smf;                 // [j][d] 32 KB
    float* colsum = smf + NS * ND;
    for (int r = 0; r < 16; ++r) qs[t + r * 512] = q[(size_t)b * NS * ND + t + r * 512];
    __syncthreads();
    if (t < ND) {
      float s = 0.f;
      for (int jj = 0; jj < NS; ++jj) s += qs[jj * ND + t];
      colsum[t] = s;
    }
    __syncthreads();
    if (t < ND) {
      float a2 = 0.f;
      for (int d = 0; d < ND; ++d) a2 += gb2[d * ND + t] * colsum[d];
      bias_agg[b * ND + t] = a2;
    }
  }
}

// ---------------------------------------------------------------------------
// k2: one wg (512 thr, 8 waves) per (b,j). MFMA bf16 16x16x32, fp32 accum.
//   P[i][e] = sum_f gelu(A_t[f][i]+Btj[f]) * W2h[f][e],  M=128,N=64,K=256
// Register prefetch of next chunk's A/W global loads overlaps MFMA.
// ---------------------------------------------------------------------------
constexpr int HLD = 72;  // ushort stride: 144 B -> frag reads 2-way max

__global__ __launch_bounds__(512) void k2_main(const float* __restrict__ A_t,
                                               const float* __restrict__ Bt,
                                               const unsigned short* __restrict__ W2h,
                                               float* __restrict__ P) {
  const int b = blockIdx.x / NS, j = blockIdx.x % NS;
  const int t = threadIdx.x;
  const int lane = t & 63, w = t >> 6;
  __shared__ float Btj[NF];
  __shared__ __align__(16) unsigned short Hc[NS * HLD];  // [i][f] 18432 B
  __shared__ __align__(16) unsigned short Wc[ND * HLD];  // [e][f]  9216 B
  if (t < NF) Btj[t] = Bt[((size_t)b * NS + j) * NF + t];

  const unsigned short* Whbj = W2h + (size_t)(b * NS + j) * NF * ND;
  const float* Ab = A_t + (size_t)b * NF * NS;

  const int wi = (w & 3) * 32, we = (w >> 2) * 32;
  const int m = lane & 15, quad = lane >> 4;
  const int hi = (w & 1) * 64 + lane, hoct0 = w >> 1;  // H staging: i, f-oct base
  const int wei = t & 63, woct = w;                     // W staging: e, f-oct

  floatx4 acc[2][2];
  #pragma unroll
  for (int a0 = 0; a0 < 2; ++a0)
    #pragma unroll
    for (int a1 = 0; a1 < 2; ++a1) acc[a0][a1] = (floatx4)0.f;

  // prologue: prefetch chunk 0
  unsigned short wvv[8];
  #pragma unroll
  for (int r = 0; r < 8; ++r)
    wvv[r] = Whbj[(size_t)(woct * 8 + r) * ND + wei];
  float ar[2][8];
  #pragma unroll
  for (int s = 0; s < 2; ++s)
    #pragma unroll
    for (int r = 0; r < 8; ++r)
      ar[s][r] = Ab[(size_t)((hoct0 + 4 * s) * 8 + r) * NS + hi];
  __syncthreads();  // Btj visible

  for (int c = 0; c < NF / 64; ++c) {
    // gelu + pack for chunk c (overlaps other waves' MFMA of c-1)
    ushort8 hv[2];
    #pragma unroll
    for (int s = 0; s < 2; ++s) {
      float hvf[8];
      #pragma unroll
      for (int r = 0; r < 8; ++r) {
        const int fl = c * 64 + (hoct0 + 4 * s) * 8 + r;
        hvf[r] = gelu_fast(ar[s][r] + Btj[fl]);
      }
      hv[s] = pack_bf16x8(hvf);
    }
    union { unsigned short a[8]; ushort8 v; } wu;
    #pragma unroll
    for (int r = 0; r < 8; ++r) wu.a[r] = wvv[r];
    if (c > 0) __syncthreads();  // prev MFMA done reading LDS
    *(ushort8*)&Wc[wei * HLD + woct * 8] = wu.v;
    *(ushort8*)&Hc[hi * HLD + hoct0 * 8] = hv[0];
    *(ushort8*)&Hc[hi * HLD + (hoct0 + 4) * 8] = hv[1];
    if (c < NF / 64 - 1) {  // prefetch chunk c+1 (in flight across barrier + MFMA)
      #pragma unroll
      for (int r = 0; r < 8; ++r)
        wvv[r] = Whbj[(size_t)((c + 1) * 64 + woct * 8 + r) * ND + wei];
      #pragma unroll
      for (int s = 0; s < 2; ++s)
        #pragma unroll
        for (int r = 0; r < 8; ++r)
          ar[s][r] = Ab[(size_t)((c + 1) * 64 + (hoct0 + 4 * s) * 8 + r) * NS + hi];
    }
    __syncthreads();
    // MFMA: 2 k-tiles of 32 per chunk
    #pragma unroll
    for (int kk = 0; kk < 2; ++kk) {
      short8 afr[2], bfr[2];
      #pragma unroll
      for (int ti = 0; ti < 2; ++ti)
        afr[ti] = *(const short8*)&Hc[(wi + ti * 16 + m) * HLD + kk * 32 + quad * 8];
      #pragma unroll
      for (int te = 0; te < 2; ++te)
        bfr[te] = *(const short8*)&Wc[(we + te * 16 + m) * HLD + kk * 32 + quad * 8];
      #pragma unroll
      for (int ti = 0; ti < 2; ++ti)
        #pragma unroll
        for (int te = 0; te < 2; ++te)
          acc[ti][te] = __builtin_amdgcn_mfma_f32_16x16x32_bf16(
              afr[ti], bfr[te], acc[ti][te], 0, 0, 0);
    }
  }
  // epilogue: D layout row=(lane>>4)*4+reg, col=lane&15
  float* Pbj = P + ((size_t)b * NS + j) * NS * ND;
  #pragma unroll
  for (int ti = 0; ti < 2; ++ti)
    #pragma unroll
    for (int te = 0; te < 2; ++te)
      #pragma unroll
      for (int r = 0; r < 4; ++r) {
        const int row = wi + ti * 16 + quad * 4 + r;
        const int col = we + te * 16 + m;
        Pbj[(size_t)row * ND + col] = acc[ti][te][r];
      }
}

// ---------------------------------------------------------------------------
// k3: one wg (512 thr) per (b,i): agg-reduce over j, LN1, MLP, LN2 -> out
// ---------------------------------------------------------------------------
__global__ __launch_bounds__(512) void k3_epi(const float* __restrict__ q,
                                              const float* __restrict__ P,
                                              const float* __restrict__ bias_agg,
                                              const float* __restrict__ mw1,
                                              const float* __restrict__ mb1,
                                              const float* __restrict__ mw2,
                                              const float* __restrict__ mb2,
                                              const float* __restrict__ ln1g,
                                              const float* __restrict__ ln1b,
                                              const float* __restrict__ ln2g,
                                              const float* __restrict__ ln2b,
                                              float* __restrict__ out) {
  const int b = blockIdx.x / NS, i = blockIdx.x % NS;
  const int t = threadIdx.x;
  const int e = t & 63, g = t >> 6;
  __shared__ float red[8 * ND];
  __shared__ float phi1[ND];
  __shared__ float hid[NF];
  const float* Pb = P + (size_t)b * NS * NS * ND;
  float s = 0.f;
  #pragma unroll 4
  for (int m0 = 0; m0 < 16; ++m0) {
    const int jj = g * 16 + m0;
    s += Pb[((size_t)jj * NS + i) * ND + e];
  }
  red[t] = s;
  __syncthreads();
  if (t < ND) {
    float agg = bias_agg[b * ND + e];
    #pragma unroll
    for (int gg = 0; gg < 8; ++gg) agg += red[gg * ND + e];
    const float x = q[((size_t)b * NS + i) * ND + e] + agg;
    float sum = x, sumsq = x * x;
    #pragma unroll
    for (int off = 32; off >= 1; off >>= 1) {
      sum += __shfl_xor(sum, off);
      sumsq += __shfl_xor(sumsq, off);
    }
    const float mu = sum * (1.f / 64.f);
    const float var = sumsq * (1.f / 64.f) - mu * mu;
    const float inv = rsqrtf(var + 1e-5f);
    phi1[e] = (x - mu) * inv * ln1g[e] + ln1b[e];
  }
  __syncthreads();
  if (t < NF) {
    float h = mb1[t];
    #pragma unroll 8
    for (int d = 0; d < ND; ++d) h += phi1[d] * mw1[d * NF + t];
    hid[t] = gelu_fast(h);
  }
  __syncthreads();
  {
    float p = 0.f;
    #pragma unroll 8
    for (int m0 = 0; m0 < 32; ++m0) {
      const int f = g * 32 + m0;
      p += hid[f] * mw2[f * ND + e];
    }
    red[t] = p;
  }
  __syncthreads();
  if (t < ND) {
    float mlp = mb2[e];
    #pragma unroll
    for (int gg = 0; gg < 8; ++gg) mlp += red[gg * ND + e];
    const float x = phi1[e] + mlp;
    float sum = x, sumsq = x * x;
    #pragma unroll
    for (int off = 32; off >= 1; off >>= 1) {
      sum += __shfl_xor(sum, off);
      sumsq += __shfl_xor(sumsq, off);
    }
    const float mu = sum * (1.f / 64.f);
    const float var = sumsq * (1.f / 64.f) - mu * mu;
    const float inv = rsqrtf(var + 1e-5f);
    out[((size_t)b * NS + i) * ND + e] = (x - mu) * inv * ln2g[e] + ln2b[e];
  }
}

}  // namespace

extern "C" void kernel_launch(void* const* d_in, const int* in_sizes, int n_in,
                              void* d_out, int out_size, void* d_ws, size_t ws_size,
                              hipStream_t stream) {
  const float* q    = (const float*)d_in[0];
  const float* gw1  = (const float*)d_in[1];
  const float* gb1  = (const float*)d_in[2];
  const float* gw2  = (const float*)d_in[3];
  const float* gb2  = (const float*)d_in[4];
  const float* mw1  = (const float*)d_in[5];
  const float* mb1  = (const float*)d_in[6];
  const float* mw2  = (const float*)d_in[7];
  const float* mb2  = (const float*)d_in[8];
  const float* ln1g = (const float*)d_in[9];
  const float* ln1b = (const float*)d_in[10];
  const float* ln2g = (const float*)d_in[11];
  const float* ln2b = (const float*)d_in[12];
  float* out = (float*)d_out;
  float* ws  = (float*)d_ws;

  unsigned short* W2h = (unsigned short*)(ws + OFF_W2H);
  float* Pp   = ws + OFF_P;
  float* A_t  = ws + OFF_AT;
  float* Bt   = ws + OFF_BT;
  float* bias = ws + OFF_BIAS;

  kA_pre<<<194, 512, 0, stream>>>(q, gw1, gb1, gw2, gb2, A_t, Bt, W2h, bias);
  k2_main<<<NB * NS, 512, 0, stream>>>(A_t, Bt, W2h, Pp);
  k3_epi<<<NB * NS, 512, 0, stream>>>(q, Pp, bias, mw1, mb1, mw2, mb2,
                                      ln1g, ln1b, ln2g, ln2b, out);
}

// Round 5
// 107.429 us; speedup vs baseline: 1.3291x; 1.0187x over previous
//
#include <hip/hip_runtime.h>
#include <hip/hip_bf16.h>
#include <math.h>

namespace {

constexpr int NB = 2, NS = 128, ND = 64, NF = 256;

typedef __attribute__((ext_vector_type(8))) short short8;
typedef __attribute__((ext_vector_type(8))) unsigned short ushort8;
typedef __attribute__((ext_vector_type(4))) float floatx4;

// workspace offsets (float units)
constexpr size_t OFF_W2H  = 0;                                   // [B][S(j)][F][D] bf16
constexpr size_t SZ_W2H   = (size_t)NB * NS * NF * ND / 2;       // ushorts in float space
constexpr size_t OFF_P    = OFF_W2H + SZ_W2H;                    // [B][S(j)][S(i)][D] bf16
constexpr size_t SZ_P     = (size_t)NB * NS * NS * ND / 2;       // ushorts in float space
constexpr size_t OFF_AT   = OFF_P + SZ_P;                        // [B][F][S(i)] fp32
constexpr size_t SZ_AT    = (size_t)NB * NF * NS;
constexpr size_t OFF_BT   = OFF_AT + SZ_AT;                      // [B][S(j)][F] fp32 (+gb1)
constexpr size_t SZ_BT    = (size_t)NB * NS * NF;
constexpr size_t OFF_BIAS = OFF_BT + SZ_BT;                      // [B][D]

// A&S 7.1.26 erf: |err| <= 1.5e-7, branchless.
__device__ __forceinline__ float gelu_fast(float x) {
  const float xs = fabsf(x) * 0.70710678118654752f;
  const float t = __builtin_amdgcn_rcpf(fmaf(0.3275911f, xs, 1.0f));
  float p = fmaf(1.061405429f, t, -1.453152027f);
  p = fmaf(p, t, 1.421413741f);
  p = fmaf(p, t, -0.284496736f);
  p = fmaf(p, t, 0.254829592f);
  p *= t;
  const float e = __expf(-xs * xs);
  const float erf_ax = fmaf(-p, e, 1.0f);
  const float erf_x = copysignf(erf_ax, x);
  return 0.5f * x * (1.0f + erf_x);
}

__device__ __forceinline__ ushort8 pack_bf16x8(const float v[8]) {
  union { __hip_bfloat162 b2[4]; ushort8 u; } u;
  #pragma unroll
  for (int p = 0; p < 4; ++p)
    u.b2[p] = __float22bfloat162_rn(make_float2(v[2 * p], v[2 * p + 1]));
  return u.u;
}

__device__ __forceinline__ float bf16u_to_f(unsigned short u) {
  return __uint_as_float((unsigned)u << 16);
}

// ---------------------------------------------------------------------------
// kA (512 thr): blocks [0,128)   : A_t / Bt  (2 i's per block)
//               blocks [128,192) : W2h[b][j][f][e] bf16 via MFMA (1 f/wave)
//               blocks [192,194) : bias_agg[b][e]
// ---------------------------------------------------------------------------
__global__ __launch_bounds__(512) void kA_pre(const float* __restrict__ q,
                                              const float* __restrict__ gw1,
                                              const float* __restrict__ gb1,
                                              const float* __restrict__ gw2,
                                              const float* __restrict__ gb2,
                                              float* __restrict__ A_t,
                                              float* __restrict__ Bt,
                                              unsigned short* __restrict__ W2h,
                                              float* __restrict__ bias_agg) {
  __shared__ __align__(16) unsigned short smem_u[128 * 64 + 8 * 64 * 40];  // 57344 B
  float* smf = (float*)smem_u;
  const int t = threadIdx.x, bid = blockIdx.x;

  if (bid < 128) {
    // ---- A_t / Bt ----
    const int b = bid >> 6, ip = bid & 63;
    const int half = t >> 8, f = t & 255;
    const int i = ip * 2 + half;
    float* qrow = smf;  // [2][64]
    if (f < 64) qrow[half * 64 + f] = q[((size_t)b * NS + i) * ND + f];
    __syncthreads();
    float a = 0.f, bb = gb1[f];
    #pragma unroll 8
    for (int d = 0; d < ND; ++d) {
      const float qd = qrow[half * 64 + d];
      a  += qd * gw1[d * NF + f];
      bb += qd * gw1[(ND + d) * NF + f];
    }
    A_t[((size_t)b * NF + f) * NS + i] = a;
    Bt[((size_t)b * NS + i) * NF + f] = bb;
  } else if (bid < 192) {
    // ---- W2h via MFMA: W2[b][j][f][e] = sum_d q[b][j][d] * gw2[f][d*64+e] ----
    const int idx = bid - 128;
    const int b = idx >> 5, f0 = (idx & 31) * 8;
    unsigned short* qbf = smem_u;             // [j][64] bf16, oct xor-swizzled by (j&7)
    unsigned short* Gt  = smem_u + 128 * 64;  // [f'][e][40] bf16 (d-contig, pad 40)
    {
      const int jq = t >> 1, half = t & 1;
      const float* src = q + ((size_t)b * NS + jq) * ND + half * 32;
      #pragma unroll
      for (int p = 0; p < 4; ++p) {
        float v[8];
        #pragma unroll
        for (int r = 0; r < 8; ++r) v[r] = src[p * 8 + r];
        const int oct = half * 4 + p;
        const int col = oct ^ (jq & 7);
        *(ushort8*)&qbf[jq * 64 + col * 8] = pack_bf16x8(v);
      }
    }
    const int lane = t & 63, w = t >> 6;
    const int f = f0 + w;
    const int m = lane & 15, quad = lane >> 4;
    const int te = t & 63, tf = t >> 6;
    floatx4 acc[8][4];
    #pragma unroll
    for (int ti = 0; ti < 8; ++ti)
      #pragma unroll
      for (int tn = 0; tn < 4; ++tn) acc[ti][tn] = (floatx4)0.f;

    for (int dc = 0; dc < 2; ++dc) {
      __syncthreads();
      const float* gsrc = gw2 + (size_t)(f0 + tf) * (ND * ND) + (size_t)(dc * 32) * ND + te;
      #pragma unroll
      for (int p = 0; p < 4; ++p) {
        float gv[8];
        #pragma unroll
        for (int r = 0; r < 8; ++r) gv[r] = gsrc[(size_t)(p * 8 + r) * ND];
        *(ushort8*)&Gt[tf * 2560 + te * 40 + p * 8] = pack_bf16x8(gv);
      }
      __syncthreads();
      short8 bfr[4];
      #pragma unroll
      for (int tn = 0; tn < 4; ++tn)
        bfr[tn] = *(const short8*)&Gt[w * 2560 + (tn * 16 + m) * 40 + quad * 8];
      #pragma unroll
      for (int ti = 0; ti < 8; ++ti) {
        const int jr = ti * 16 + m;
        const int col = (dc * 4 + quad) ^ (jr & 7);
        const short8 afr = *(const short8*)&qbf[jr * 64 + col * 8];
        #pragma unroll
        for (int tn = 0; tn < 4; ++tn)
          acc[ti][tn] = __builtin_amdgcn_mfma_f32_16x16x32_bf16(afr, bfr[tn],
                                                                acc[ti][tn], 0, 0, 0);
      }
    }
    __hip_bfloat16* Wh = (__hip_bfloat16*)W2h;
    #pragma unroll
    for (int ti = 0; ti < 8; ++ti)
      #pragma unroll
      for (int r = 0; r < 4; ++r) {
        const int jr = ti * 16 + quad * 4 + r;
        __hip_bfloat16* dst = Wh + ((size_t)(b * NS + jr) * NF + f) * ND;
        #pragma unroll
        for (int tn = 0; tn < 4; ++tn)
          dst[tn * 16 + m] = __float2bfloat16(acc[ti][tn][r]);
      }
  } else {
    // ---- bias_agg ----
    const int b = bid - 192;
    float* qs = smf;
    float* colsum = smf + NS * ND;
    for (int r = 0; r < 16; ++r) qs[t + r * 512] = q[(size_t)b * NS * ND + t + r * 512];
    __syncthreads();
    if (t < ND) {
      float s = 0.f;
      for (int jj = 0; jj < NS; ++jj) s += qs[jj * ND + t];
      colsum[t] = s;
    }
    __syncthreads();
    if (t < ND) {
      float a2 = 0.f;
      for (int d = 0; d < ND; ++d) a2 += gb2[d * ND + t] * colsum[d];
      bias_agg[b * ND + t] = a2;
    }
  }
}

// ---------------------------------------------------------------------------
// k2: one wg (512 thr, 8 waves) per (b,j). MFMA bf16 16x16x32, fp32 accum.
//   P[i][e] = sum_f gelu(A_t[f][i]+Btj[f]) * W2h[f][e],  M=128,N=64,K=256
// Output P stored bf16 (halves P HBM traffic; error << threshold).
// ---------------------------------------------------------------------------
constexpr int HLD = 72;  // ushort stride: 144 B -> frag reads 2-way max

__global__ __launch_bounds__(512) void k2_main(const float* __restrict__ A_t,
                                               const float* __restrict__ Bt,
                                               const unsigned short* __restrict__ W2h,
                                               unsigned short* __restrict__ P) {
  const int b = blockIdx.x / NS, j = blockIdx.x % NS;
  const int t = threadIdx.x;
  const int lane = t & 63, w = t >> 6;
  __shared__ float Btj[NF];
  __shared__ __align__(16) unsigned short Hc[NS * HLD];
  __shared__ __align__(16) unsigned short Wc[ND * HLD];
  if (t < NF) Btj[t] = Bt[((size_t)b * NS + j) * NF + t];

  const unsigned short* Whbj = W2h + (size_t)(b * NS + j) * NF * ND;
  const float* Ab = A_t + (size_t)b * NF * NS;

  const int wi = (w & 3) * 32, we = (w >> 2) * 32;
  const int m = lane & 15, quad = lane >> 4;
  const int hi = (w & 1) * 64 + lane, hoct0 = w >> 1;
  const int wei = t & 63, woct = w;

  floatx4 acc[2][2];
  #pragma unroll
  for (int a0 = 0; a0 < 2; ++a0)
    #pragma unroll
    for (int a1 = 0; a1 < 2; ++a1) acc[a0][a1] = (floatx4)0.f;

  unsigned short wvv[8];
  #pragma unroll
  for (int r = 0; r < 8; ++r)
    wvv[r] = Whbj[(size_t)(woct * 8 + r) * ND + wei];
  float ar[2][8];
  #pragma unroll
  for (int s = 0; s < 2; ++s)
    #pragma unroll
    for (int r = 0; r < 8; ++r)
      ar[s][r] = Ab[(size_t)((hoct0 + 4 * s) * 8 + r) * NS + hi];
  __syncthreads();  // Btj visible

  for (int c = 0; c < NF / 64; ++c) {
    ushort8 hv[2];
    #pragma unroll
    for (int s = 0; s < 2; ++s) {
      float hvf[8];
      #pragma unroll
      for (int r = 0; r < 8; ++r) {
        const int fl = c * 64 + (hoct0 + 4 * s) * 8 + r;
        hvf[r] = gelu_fast(ar[s][r] + Btj[fl]);
      }
      hv[s] = pack_bf16x8(hvf);
    }
    union { unsigned short a[8]; ushort8 v; } wu;
    #pragma unroll
    for (int r = 0; r < 8; ++r) wu.a[r] = wvv[r];
    if (c > 0) __syncthreads();
    *(ushort8*)&Wc[wei * HLD + woct * 8] = wu.v;
    *(ushort8*)&Hc[hi * HLD + hoct0 * 8] = hv[0];
    *(ushort8*)&Hc[hi * HLD + (hoct0 + 4) * 8] = hv[1];
    if (c < NF / 64 - 1) {
      #pragma unroll
      for (int r = 0; r < 8; ++r)
        wvv[r] = Whbj[(size_t)((c + 1) * 64 + woct * 8 + r) * ND + wei];
      #pragma unroll
      for (int s = 0; s < 2; ++s)
        #pragma unroll
        for (int r = 0; r < 8; ++r)
          ar[s][r] = Ab[(size_t)((c + 1) * 64 + (hoct0 + 4 * s) * 8 + r) * NS + hi];
    }
    __syncthreads();
    #pragma unroll
    for (int kk = 0; kk < 2; ++kk) {
      short8 afr[2], bfr[2];
      #pragma unroll
      for (int ti = 0; ti < 2; ++ti)
        afr[ti] = *(const short8*)&Hc[(wi + ti * 16 + m) * HLD + kk * 32 + quad * 8];
      #pragma unroll
      for (int te = 0; te < 2; ++te)
        bfr[te] = *(const short8*)&Wc[(we + te * 16 + m) * HLD + kk * 32 + quad * 8];
      #pragma unroll
      for (int ti = 0; ti < 2; ++ti)
        #pragma unroll
        for (int te = 0; te < 2; ++te)
          acc[ti][te] = __builtin_amdgcn_mfma_f32_16x16x32_bf16(
              afr[ti], bfr[te], acc[ti][te], 0, 0, 0);
    }
  }
  // epilogue: D layout row=(lane>>4)*4+reg, col=lane&15; store bf16
  __hip_bfloat16* Pbj = (__hip_bfloat16*)(P + (size_t)(b * NS + j) * NS * ND);
  #pragma unroll
  for (int ti = 0; ti < 2; ++ti)
    #pragma unroll
    for (int te = 0; te < 2; ++te)
      #pragma unroll
      for (int r = 0; r < 4; ++r) {
        const int row = wi + ti * 16 + quad * 4 + r;
        const int col = we + te * 16 + m;
        Pbj[(size_t)row * ND + col] = __float2bfloat16(acc[ti][te][r]);
      }
}

// ---------------------------------------------------------------------------
// k3: one wg (512 thr) per (b,i): agg-reduce over j (bf16 P), LN1, MLP, LN2
// ---------------------------------------------------------------------------
__global__ __launch_bounds__(512) void k3_epi(const float* __restrict__ q,
                                              const unsigned short* __restrict__ P,
                                              const float* __restrict__ bias_agg,
                                              const float* __restrict__ mw1,
                                              const float* __restrict__ mb1,
                                              const float* __restrict__ mw2,
                                              const float* __restrict__ mb2,
                                              const float* __restrict__ ln1g,
                                              const float* __restrict__ ln1b,
                                              const float* __restrict__ ln2g,
                                              const float* __restrict__ ln2b,
                                              float* __restrict__ out) {
  const int b = blockIdx.x / NS, i = blockIdx.x % NS;
  const int t = threadIdx.x;
  const int e = t & 63, g = t >> 6;
  __shared__ float red[8 * ND];
  __shared__ float phi1[ND];
  __shared__ float hid[NF];
  const unsigned short* Pb = P + (size_t)b * NS * NS * ND;
  float s = 0.f;
  #pragma unroll 4
  for (int m0 = 0; m0 < 16; ++m0) {
    const int jj = g * 16 + m0;
    s += bf16u_to_f(Pb[((size_t)jj * NS + i) * ND + e]);
  }
  red[t] = s;
  __syncthreads();
  if (t < ND) {
    float agg = bias_agg[b * ND + e];
    #pragma unroll
    for (int gg = 0; gg < 8; ++gg) agg += red[gg * ND + e];
    const float x = q[((size_t)b * NS + i) * ND + e] + agg;
    float sum = x, sumsq = x * x;
    #pragma unroll
    for (int off = 32; off >= 1; off >>= 1) {
      sum += __shfl_xor(sum, off);
      sumsq += __shfl_xor(sumsq, off);
    }
    const float mu = sum * (1.f / 64.f);
    const float var = sumsq * (1.f / 64.f) - mu * mu;
    const float inv = rsqrtf(var + 1e-5f);
    phi1[e] = (x - mu) * inv * ln1g[e] + ln1b[e];
  }
  __syncthreads();
  if (t < NF) {
    float h = mb1[t];
    #pragma unroll 8
    for (int d = 0; d < ND; ++d) h += phi1[d] * mw1[d * NF + t];
    hid[t] = gelu_fast(h);
  }
  __syncthreads();
  {
    float p = 0.f;
    #pragma unroll 8
    for (int m0 = 0; m0 < 32; ++m0) {
      const int f = g * 32 + m0;
      p += hid[f] * mw2[f * ND + e];
    }
    red[t] = p;
  }
  __syncthreads();
  if (t < ND) {
    float mlp = mb2[e];
    #pragma unroll
    for (int gg = 0; gg < 8; ++gg) mlp += red[gg * ND + e];
    const float x = phi1[e] + mlp;
    float sum = x, sumsq = x * x;
    #pragma unroll
    for (int off = 32; off >= 1; off >>= 1) {
      sum += __shfl_xor(sum, off);
      sumsq += __shfl_xor(sumsq, off);
    }
    const float mu = sum * (1.f / 64.f);
    const float var = sumsq * (1.f / 64.f) - mu * mu;
    const float inv = rsqrtf(var + 1e-5f);
    out[((size_t)b * NS + i) * ND + e] = (x - mu) * inv * ln2g[e] + ln2b[e];
  }
}

}  // namespace

extern "C" void kernel_launch(void* const* d_in, const int* in_sizes, int n_in,
                              void* d_out, int out_size, void* d_ws, size_t ws_size,
                              hipStream_t stream) {
  const float* q    = (const float*)d_in[0];
  const float* gw1  = (const float*)d_in[1];
  const float* gb1  = (const float*)d_in[2];
  const float* gw2  = (const float*)d_in[3];
  const float* gb2  = (const float*)d_in[4];
  const float* mw1  = (const float*)d_in[5];
  const float* mb1  = (const float*)d_in[6];
  const float* mw2  = (const float*)d_in[7];
  const float* mb2  = (const float*)d_in[8];
  const float* ln1g = (const float*)d_in[9];
  const float* ln1b = (const float*)d_in[10];
  const float* ln2g = (const float*)d_in[11];
  const float* ln2b = (const float*)d_in[12];
  float* out = (float*)d_out;
  float* ws  = (float*)d_ws;

  unsigned short* W2h = (unsigned short*)(ws + OFF_W2H);
  unsigned short* Pp  = (unsigned short*)(ws + OFF_P);
  float* A_t  = ws + OFF_AT;
  float* Bt   = ws + OFF_BT;
  float* bias = ws + OFF_BIAS;

  kA_pre<<<194, 512, 0, stream>>>(q, gw1, gb1, gw2, gb2, A_t, Bt, W2h, bias);
  k2_main<<<NB * NS, 512, 0, stream>>>(A_t, Bt, W2h, Pp);
  k3_epi<<<NB * NS, 512, 0, stream>>>(q, Pp, bias, mw1, mb1, mw2, mb2,
                                      ln1g, ln1b, ln2g, ln2b, out);
}